// Round 8
// baseline (227.601 us; speedup 1.0000x reference)
//
#include <hip/hip_runtime.h>
#include <hip/hip_bf16.h>

typedef __attribute__((ext_vector_type(8))) short short8;
typedef __attribute__((ext_vector_type(4))) short short4v;
typedef __attribute__((ext_vector_type(4))) float f32x4;
typedef __attribute__((ext_vector_type(4))) int i32x4;

static __device__ __forceinline__ short f2bf(float f) {
    __hip_bfloat16 h = __float2bfloat16(f);
    return __builtin_bit_cast(short, h);
}

static __device__ __forceinline__ float exp2fast(float x) {
    float r;
    asm("v_exp_f32 %0, %1" : "=v"(r) : "v"(x));
    return r;
}

static __device__ __forceinline__ unsigned cvt_pk_bf16(float a, float b) {
    unsigned r;
    asm("v_cvt_pk_bf16_f32 %0, %1, %2" : "=v"(r) : "v"(a), "v"(b));
    return r;
}

#define GLOAD16(g, l) __builtin_amdgcn_global_load_lds( \
    (const __attribute__((address_space(1))) void*)(g), \
    (__attribute__((address_space(3))) void*)(l), 16, 0, 0)

// ---------------- fused fp32 -> bf16 convert (7 arrays, grid.y selects) ----------------
__global__ __launch_bounds__(256) void convert_all(
        const float* __restrict__ q, const float* __restrict__ k, const float* __restrict__ v,
        const float* __restrict__ wq, const float* __restrict__ wk,
        const float* __restrict__ wv, const float* __restrict__ wo,
        short* __restrict__ oq, short* __restrict__ ok, short* __restrict__ ov,
        short* __restrict__ owq, short* __restrict__ owk,
        short* __restrict__ owv, short* __restrict__ owo) {
    const int y = blockIdx.y;
    const float* in;
    short* out;
    int n4;
    switch (y) {
        case 0: in = q;  out = oq;  n4 = 1048576; break;
        case 1: in = k;  out = ok;  n4 = 1048576; break;
        case 2: in = v;  out = ov;  n4 = 1048576; break;
        case 3: in = wq; out = owq; n4 = 262144;  break;
        case 4: in = wk; out = owk; n4 = 262144;  break;
        case 5: in = wv; out = owv; n4 = 262144;  break;
        default: in = wo; out = owo; n4 = 262144; break;
    }
    int i = blockIdx.x * blockDim.x + threadIdx.x;
    int stride = gridDim.x * blockDim.x;
    for (; i < n4; i += stride) {
        f32x4 vv = reinterpret_cast<const f32x4*>(in)[i];
        short4v o;
        o.x = f2bf(vv.x); o.y = f2bf(vv.y); o.z = f2bf(vv.z); o.w = f2bf(vv.w);
        reinterpret_cast<short4v*>(out)[i] = o;
    }
}

// ---------------- fused QKV projection GEMM (m97 structure) ----------------
// 128x128 tile, 4 waves (2x2), BK=64 single-buffered gload_lds + both-sides XOR
// swizzle. grid = (256, 3). V output (y==2) is transposed via an LDS round-trip
// so global stores are 64B-contiguous (direct d-major scatter was 8B/4KB-stride).
__global__ __launch_bounds__(256, 3) void gemm_qkv(
        const short* __restrict__ Qb, const short* __restrict__ Kb, const short* __restrict__ Vb,
        const short* __restrict__ Wq, const short* __restrict__ Wk, const short* __restrict__ Wv,
        const float* __restrict__ bq, const float* __restrict__ bk, const float* __restrict__ bv,
        short* __restrict__ q_, short* __restrict__ k_, short* __restrict__ vT) {
    __shared__ __align__(16) short lds[2 * 128 * 64];   // aS | bS, reused by V epilogue
    short* aS = lds;
    short* bS = lds + 8192;
    const int tid = threadIdx.x;
    const int lane = tid & 63;
    const int w = tid >> 6;
    const int wr = w >> 1, wc = w & 1;
    const int l15 = lane & 15, lq = lane >> 4;
    const int lr = lane >> 3;
    const int lcs = ((lane & 7) ^ lr) * 8;   // pre-swizzled global col (shorts)
    const int y = blockIdx.y;
    const int wg = (blockIdx.x & 7) * 32 + (blockIdx.x >> 3);  // XCD swizzle (256%8==0)
    const int bn = wg & 7;    // N/128 = 8
    const int bm = wg >> 3;   // M/128 = 32

    const short* A = y == 0 ? Qb : y == 1 ? Kb : Vb;
    const short* W = y == 0 ? Wq : y == 1 ? Wk : Wv;
    const float* bias = y == 0 ? bq : y == 1 ? bk : bv;
    const short* Ab = A + (size_t)(bm * 128) * 1024;
    const short* Wb = W + (size_t)(bn * 128) * 1024;

    f32x4 acc[4][4] = {};

    for (int t = 0; t < 16; ++t) {
        const int k0 = t * 64;
#pragma unroll
        for (int j = 0; j < 4; ++j) {
            int r0 = w * 32 + j * 8;
            GLOAD16(&Ab[(size_t)(r0 + lr) * 1024 + k0 + lcs], &aS[r0 * 64]);
        }
#pragma unroll
        for (int j = 0; j < 4; ++j) {
            int r0 = w * 32 + j * 8;
            GLOAD16(&Wb[(size_t)(r0 + lr) * 1024 + k0 + lcs], &bS[r0 * 64]);
        }
        asm volatile("s_waitcnt vmcnt(0)" ::: "memory");
        __builtin_amdgcn_s_barrier();
#pragma unroll
        for (int kf = 0; kf < 2; ++kf) {
            const int ck = ((kf * 4 + lq) ^ (l15 & 7)) * 8;
            short8 af[4], bfr[4];
#pragma unroll
            for (int mi = 0; mi < 4; ++mi)
                af[mi] = *reinterpret_cast<const short8*>(
                    &aS[(wr * 64 + mi * 16 + l15) * 64 + ck]);
#pragma unroll
            for (int ni = 0; ni < 4; ++ni)
                bfr[ni] = *reinterpret_cast<const short8*>(
                    &bS[(wc * 64 + ni * 16 + l15) * 64 + ck]);
#pragma unroll
            for (int mi = 0; mi < 4; ++mi)
#pragma unroll
                for (int ni = 0; ni < 4; ++ni)
                    acc[mi][ni] = __builtin_amdgcn_mfma_f32_16x16x32_bf16(
                        af[mi], bfr[ni], acc[mi][ni], 0, 0, 0);
        }
        asm volatile("s_waitcnt lgkmcnt(0)" ::: "memory");
        __builtin_amdgcn_sched_barrier(0);
        __builtin_amdgcn_s_barrier();
    }

    // q pre-scaled by 1/sqrt(64) * log2(e) so attention scores are log2-domain
    const float QSCALE = 0.125f * 1.44269504f;
    if (y < 2) {
#pragma unroll
        for (int mi = 0; mi < 4; ++mi) {
#pragma unroll
            for (int ni = 0; ni < 4; ++ni) {
#pragma unroll
                for (int i = 0; i < 4; ++i) {
                    int m = bm * 128 + wr * 64 + mi * 16 + lq * 4 + i;
                    int n = bn * 128 + wc * 64 + ni * 16 + l15;
                    float v = acc[mi][ni][i] + bias[n];
                    int b = m >> 11, s = m & 2047, h = n >> 6, d = n & 63;
                    if (y == 0)
                        q_[((size_t)(b * 16 + h) * 2048 + s) * 64 + d] = f2bf(v * QSCALE);
                    else
                        k_[((size_t)(b * 16 + h) * 2048 + s) * 64 + d] = f2bf(v);
                }
            }
        }
    } else {
        // V: transpose in LDS. Write [n_local][m 16B-chunk ^ (n&15)] then read
        // rows and store 64B-contiguous (4 lanes per row).
#pragma unroll
        for (int mi = 0; mi < 4; ++mi) {
#pragma unroll
            for (int ni = 0; ni < 4; ++ni) {
                int nl = wc * 64 + ni * 16 + l15;
                int cc = wr * 8 + mi * 2 + (lq >> 1);
                int addr = nl * 128 + ((cc ^ (nl & 15)) * 8) + (lq & 1) * 4;
                short4v pk;
                pk.x = f2bf(acc[mi][ni][0] + bias[bn * 128 + nl]);
                pk.y = f2bf(acc[mi][ni][1] + bias[bn * 128 + nl]);
                pk.z = f2bf(acc[mi][ni][2] + bias[bn * 128 + nl]);
                pk.w = f2bf(acc[mi][ni][3] + bias[bn * 128 + nl]);
                *reinterpret_cast<short4v*>(&lds[addr]) = pk;
            }
        }
        __syncthreads();
        const int bb = bm >> 4;
        const int s0base = (bm & 15) * 128;
#pragma unroll
        for (int j = 0; j < 8; ++j) {
            int rr = w * 32 + (j & 1) * 16 + (lane >> 2);
            int cc2 = (j >> 1) * 4 + (lane & 3);
            short8 val = *reinterpret_cast<const short8*>(
                &lds[rr * 128 + ((cc2 ^ (rr & 15)) * 8)]);
            int n = bn * 128 + rr;
            int hh = n >> 6, d = n & 63;
            *reinterpret_cast<short8*>(
                &vT[((size_t)(bb * 16 + hh) * 64 + d) * 2048 + s0base + cc2 * 8]) = val;
        }
    }
}

// ---------------- output projection GEMM (m97 128x128 structure, fp32 out) ----------------
__global__ __launch_bounds__(256, 3) void gemm_o(
        const short* __restrict__ A, const short* __restrict__ W,
        const float* __restrict__ bias, float* __restrict__ out) {
    __shared__ __align__(16) short lds[2 * 128 * 64];
    short* aS = lds;
    short* bS = lds + 8192;
    const int tid = threadIdx.x;
    const int lane = tid & 63;
    const int w = tid >> 6;
    const int wr = w >> 1, wc = w & 1;
    const int l15 = lane & 15, lq = lane >> 4;
    const int lr = lane >> 3;
    const int lcs = ((lane & 7) ^ lr) * 8;
    const int wg = (blockIdx.x & 7) * 32 + (blockIdx.x >> 3);
    const int bn = wg & 7;
    const int bm = wg >> 3;
    const short* Ab = A + (size_t)(bm * 128) * 1024;
    const short* Wb = W + (size_t)(bn * 128) * 1024;

    f32x4 acc[4][4] = {};

    for (int t = 0; t < 16; ++t) {
        const int k0 = t * 64;
#pragma unroll
        for (int j = 0; j < 4; ++j) {
            int r0 = w * 32 + j * 8;
            GLOAD16(&Ab[(size_t)(r0 + lr) * 1024 + k0 + lcs], &aS[r0 * 64]);
        }
#pragma unroll
        for (int j = 0; j < 4; ++j) {
            int r0 = w * 32 + j * 8;
            GLOAD16(&Wb[(size_t)(r0 + lr) * 1024 + k0 + lcs], &bS[r0 * 64]);
        }
        asm volatile("s_waitcnt vmcnt(0)" ::: "memory");
        __builtin_amdgcn_s_barrier();
#pragma unroll
        for (int kf = 0; kf < 2; ++kf) {
            const int ck = ((kf * 4 + lq) ^ (l15 & 7)) * 8;
            short8 af[4], bfr[4];
#pragma unroll
            for (int mi = 0; mi < 4; ++mi)
                af[mi] = *reinterpret_cast<const short8*>(
                    &aS[(wr * 64 + mi * 16 + l15) * 64 + ck]);
#pragma unroll
            for (int ni = 0; ni < 4; ++ni)
                bfr[ni] = *reinterpret_cast<const short8*>(
                    &bS[(wc * 64 + ni * 16 + l15) * 64 + ck]);
#pragma unroll
            for (int mi = 0; mi < 4; ++mi)
#pragma unroll
                for (int ni = 0; ni < 4; ++ni)
                    acc[mi][ni] = __builtin_amdgcn_mfma_f32_16x16x32_bf16(
                        af[mi], bfr[ni], acc[mi][ni], 0, 0, 0);
        }
        asm volatile("s_waitcnt lgkmcnt(0)" ::: "memory");
        __builtin_amdgcn_sched_barrier(0);
        __builtin_amdgcn_s_barrier();
    }

#pragma unroll
    for (int mi = 0; mi < 4; ++mi)
#pragma unroll
        for (int ni = 0; ni < 4; ++ni)
#pragma unroll
            for (int i = 0; i < 4; ++i) {
                int m = bm * 128 + wr * 64 + mi * 16 + lq * 4 + i;
                int n = bn * 128 + wc * 64 + ni * 16 + l15;
                out[(size_t)m * 1024 + n] = acc[mi][ni][i] + bias[n];
            }
}

// ---------------- causal flash attention, fold-paired ----------------
// grid = 512 (32 bh x 16 pairs). Block owns q-tiles (p, 31-p): per-block compute
// = 33 tile-steps for every block (perfect balance); one K/V staging stream
// serves both tiles (kfr/vb fragment reads shared). Swapped QK^T, log2-domain,
// defer-max THR=8, XOR-swizzled K/V LDS, 4-lane shuffle transpose for PV-A.
__global__ __launch_bounds__(256, 2) void attn_fwd(
        const short* __restrict__ qh, const short* __restrict__ kh,
        const short* __restrict__ vT, short* __restrict__ attn) {
    __shared__ __align__(16) short kS[64 * 64];
    __shared__ __align__(16) short vS[64 * 64];
    const int tid = threadIdx.x;
    const int lane = tid & 63;
    const int l15 = lane & 15, lq = lane >> 4;
    const int w = tid >> 6;
    const int hi = (lane >> 5) & 1;
    const int bh = blockIdx.x & 31;
    const int p = blockIdx.x >> 5;             // 0..15
    const int qtL = p, qtH = 31 - p;
    const int b = bh >> 4, h = bh & 15;
    const size_t head = (size_t)bh * 2048 * 64;
    const short* qp = qh + head;
    const short* kp = kh + head;
    const short* vp = vT + head;
    const int qL0 = qtL * 64 + w * 16;
    const int qH0 = qtH * 64 + w * 16;

    short8 qfL_[2], qfH_[2];
#pragma unroll
    for (int kf = 0; kf < 2; ++kf) {
        qfL_[kf] = *reinterpret_cast<const short8*>(
            &qp[(size_t)(qL0 + l15) * 64 + kf * 32 + lq * 8]);
        qfH_[kf] = *reinterpret_cast<const short8*>(
            &qp[(size_t)(qH0 + l15) * 64 + kf * 32 + lq * 8]);
    }

    f32x4 oH[4] = {}, oL[4] = {};
    float mH = -1e30f, lH = 0.f, mL = -1e30f, lL = 0.f;

    const int sr = tid >> 3;
    const int sc8 = tid & 7;
    const int scg = sc8 * 8;
    const int sls = sr * 64 + (sc8 ^ (sr & 7)) * 8;
    const int sls2 = (sr + 32) * 64 + (sc8 ^ (sr & 7)) * 8;

    // softmax for one tile-state; fills P8 (packed bf16 pairs)
    auto softmax = [&](f32x4 (&s)[4], float& m_, float& l_, f32x4 (&o)[4],
                       unsigned (&P8)[8]) {
        float pmax = fmaxf(fmaxf(fmaxf(s[0][0], s[0][1]), fmaxf(s[0][2], s[0][3])),
                           fmaxf(fmaxf(s[1][0], s[1][1]), fmaxf(s[1][2], s[1][3])));
        pmax = fmaxf(pmax, fmaxf(fmaxf(fmaxf(s[2][0], s[2][1]), fmaxf(s[2][2], s[2][3])),
                                 fmaxf(fmaxf(s[3][0], s[3][1]), fmaxf(s[3][2], s[3][3]))));
        pmax = fmaxf(pmax, __shfl_xor(pmax, 16));
        pmax = fmaxf(pmax, __shfl_xor(pmax, 32));
        if (!__all(pmax - m_ <= 8.0f)) {
            float mnew = fmaxf(m_, pmax);
            float scl = exp2fast(m_ - mnew);
            m_ = mnew;
            l_ *= scl;
            float s0 = __shfl(scl, lq * 4 + 0);
            float s1 = __shfl(scl, lq * 4 + 1);
            float s2 = __shfl(scl, lq * 4 + 2);
            float s3 = __shfl(scl, lq * 4 + 3);
#pragma unroll
            for (int df = 0; df < 4; ++df) {
                o[df][0] *= s0; o[df][1] *= s1; o[df][2] *= s2; o[df][3] *= s3;
            }
        }
        float rsum = 0.f;
#pragma unroll
        for (int cf = 0; cf < 4; ++cf) {
            float p0 = exp2fast(s[cf][0] - m_);
            float p1 = exp2fast(s[cf][1] - m_);
            float p2 = exp2fast(s[cf][2] - m_);
            float p3 = exp2fast(s[cf][3] - m_);
            rsum += (p0 + p1) + (p2 + p3);
            P8[2 * cf]     = cvt_pk_bf16(p0, p1);
            P8[2 * cf + 1] = cvt_pk_bf16(p2, p3);
        }
        rsum += __shfl_xor(rsum, 16);
        rsum += __shfl_xor(rsum, 32);
        l_ += rsum;
    };

    const int nt = qtH + 1;
    short8 kra = *reinterpret_cast<const short8*>(&kp[(size_t)sr * 64 + scg]);
    short8 krb = *reinterpret_cast<const short8*>(&kp[(size_t)(sr + 32) * 64 + scg]);
    short8 vra = *reinterpret_cast<const short8*>(&vp[(size_t)sr * 2048 + scg]);
    short8 vrb = *reinterpret_cast<const short8*>(&vp[(size_t)(sr + 32) * 2048 + scg]);
    *reinterpret_cast<short8*>(&kS[sls]) = kra;
    *reinterpret_cast<short8*>(&kS[sls2]) = krb;
    *reinterpret_cast<short8*>(&vS[sls]) = vra;
    *reinterpret_cast<short8*>(&vS[sls2]) = vrb;
    __syncthreads();

    for (int t = 0; t < nt; ++t) {
        if (t + 1 < nt) {
            kra = *reinterpret_cast<const short8*>(
                &kp[(size_t)((t + 1) * 64 + sr) * 64 + scg]);
            krb = *reinterpret_cast<const short8*>(
                &kp[(size_t)((t + 1) * 64 + sr + 32) * 64 + scg]);
            vra = *reinterpret_cast<const short8*>(
                &vp[(size_t)sr * 2048 + (t + 1) * 64 + scg]);
            vrb = *reinterpret_cast<const short8*>(
                &vp[(size_t)(sr + 32) * 2048 + (t + 1) * 64 + scg]);
        }
        const bool la = (t <= qtL);  // block-uniform
        f32x4 sH[4] = {}, sL[4] = {};
#pragma unroll
        for (int kf = 0; kf < 2; ++kf) {
            short8 kfr[4];
#pragma unroll
            for (int cf = 0; cf < 4; ++cf)
                kfr[cf] = *reinterpret_cast<const short8*>(
                    &kS[(cf * 16 + l15) * 64 + ((kf * 4 + lq) ^ (l15 & 7)) * 8]);
#pragma unroll
            for (int cf = 0; cf < 4; ++cf)
                sH[cf] = __builtin_amdgcn_mfma_f32_16x16x32_bf16(
                    kfr[cf], qfH_[kf], sH[cf], 0, 0, 0);
            if (la) {
#pragma unroll
                for (int cf = 0; cf < 4; ++cf)
                    sL[cf] = __builtin_amdgcn_mfma_f32_16x16x32_bf16(
                        kfr[cf], qfL_[kf], sL[cf], 0, 0, 0);
            }
        }
        if (t == qtH) {
            const int q = qH0 + l15;
#pragma unroll
            for (int cf = 0; cf < 4; ++cf)
#pragma unroll
                for (int i = 0; i < 4; ++i)
                    if (t * 64 + cf * 16 + lq * 4 + i > q) sH[cf][i] = -1e30f;
        }
        if (la && t == qtL) {
            const int q = qL0 + l15;
#pragma unroll
            for (int cf = 0; cf < 4; ++cf)
#pragma unroll
                for (int i = 0; i < 4; ++i)
                    if (t * 64 + cf * 16 + lq * 4 + i > q) sL[cf][i] = -1e30f;
        }
        unsigned P8H[8], P8L[8];
        softmax(sH, mH, lH, oH, P8H);
        if (la) softmax(sL, mL, lL, oL, P8L);
        // PV: shared vb loads; shuffle-transpose per state (round-6-fixed shfl)
#pragma unroll
        for (int kk = 0; kk < 2; ++kk) {
            short8 vb[4];
#pragma unroll
            for (int df = 0; df < 4; ++df)
                vb[df] = *reinterpret_cast<const short8*>(
                    &vS[(df * 16 + l15) * 64 + ((kk * 4 + lq) ^ (l15 & 7)) * 8]);
            {
                int dw[4];
#pragma unroll
                for (int j = 0; j < 4; ++j) {
                    int src = l15 + 16 * (2 * (lq & 1) + (j >> 1));
                    int vlo = __shfl((int)P8H[4 * kk + (j & 1)], src);
                    int vhi = __shfl((int)P8H[4 * kk + 2 + (j & 1)], src);
                    dw[j] = hi ? vhi : vlo;
                }
                i32x4 dwv; dwv.x = dw[0]; dwv.y = dw[1]; dwv.z = dw[2]; dwv.w = dw[3];
                short8 pa = __builtin_bit_cast(short8, dwv);
#pragma unroll
                for (int df = 0; df < 4; ++df)
                    oH[df] = __builtin_amdgcn_mfma_f32_16x16x32_bf16(
                        pa, vb[df], oH[df], 0, 0, 0);
            }
            if (la) {
                int dw[4];
#pragma unroll
                for (int j = 0; j < 4; ++j) {
                    int src = l15 + 16 * (2 * (lq & 1) + (j >> 1));
                    int vlo = __shfl((int)P8L[4 * kk + (j & 1)], src);
                    int vhi = __shfl((int)P8L[4 * kk + 2 + (j & 1)], src);
                    dw[j] = hi ? vhi : vlo;
                }
                i32x4 dwv; dwv.x = dw[0]; dwv.y = dw[1]; dwv.z = dw[2]; dwv.w = dw[3];
                short8 pa = __builtin_bit_cast(short8, dwv);
#pragma unroll
                for (int df = 0; df < 4; ++df)
                    oL[df] = __builtin_amdgcn_mfma_f32_16x16x32_bf16(
                        pa, vb[df], oL[df], 0, 0, 0);
            }
        }
        __syncthreads();
        if (t + 1 < nt) {
            *reinterpret_cast<short8*>(&kS[sls]) = kra;
            *reinterpret_cast<short8*>(&kS[sls2]) = krb;
            *reinterpret_cast<short8*>(&vS[sls]) = vra;
            *reinterpret_cast<short8*>(&vS[sls2]) = vrb;
        }
        __syncthreads();
    }

    // epilogue: both tiles; o rows are q = q?0 + lq*4 + i
#pragma unroll
    for (int i = 0; i < 4; ++i) {
        float liH = __shfl(lH, lq * 4 + i);
        float liL = __shfl(lL, lq * 4 + i);
        float rH = 1.0f / liH;
        float rL = 1.0f / liL;
        int sgH = qH0 + lq * 4 + i;
        int sgL = qL0 + lq * 4 + i;
        size_t mrH = (size_t)b * 2048 + sgH;
        size_t mrL = (size_t)b * 2048 + sgL;
#pragma unroll
        for (int df = 0; df < 4; ++df) {
            int col = h * 64 + df * 16 + l15;
            attn[mrH * 1024 + col] = f2bf(oH[df][i] * rH);
            attn[mrL * 1024 + col] = f2bf(oL[df][i] * rL);
        }
    }
}

extern "C" void kernel_launch(void* const* d_in, const int* in_sizes, int n_in,
                              void* d_out, int out_size, void* d_ws, size_t ws_size,
                              hipStream_t stream) {
    const float* Q  = (const float*)d_in[0];
    const float* K  = (const float*)d_in[1];
    const float* V  = (const float*)d_in[2];
    // d_in[3] = causal mask, applied analytically
    const float* Wq = (const float*)d_in[4];
    const float* bq = (const float*)d_in[5];
    const float* Wk = (const float*)d_in[6];
    const float* bk = (const float*)d_in[7];
    const float* Wv = (const float*)d_in[8];
    const float* bv = (const float*)d_in[9];
    const float* Wo = (const float*)d_in[10];
    const float* bo = (const float*)d_in[11];

    char* ws = (char*)d_ws;
    short* Qb   = (short*)(ws);
    short* Kb   = (short*)(ws + 8388608);
    short* Vb   = (short*)(ws + 16777216);
    short* Wqb  = (short*)(ws + 25165824);
    short* Wkb  = (short*)(ws + 27262976);
    short* Wvb  = (short*)(ws + 29360128);
    short* Wob  = (short*)(ws + 31457280);
    short* q_   = (short*)(ws + 33554432);
    short* k_   = (short*)(ws + 41943040);
    short* vT   = (short*)(ws + 50331648);
    short* attn = Qb;  // Qb dead after gemm_qkv; reuse for attention output

    dim3 cb(256);
    convert_all<<<dim3(512, 7), cb, 0, stream>>>(Q, K, V, Wq, Wk, Wv, Wo,
                                                 Qb, Kb, Vb, Wqb, Wkb, Wvb, Wob);

    gemm_qkv<<<dim3(256, 3), cb, 0, stream>>>(Qb, Kb, Vb, Wqb, Wkb, Wvb,
                                              bq, bk, bv, q_, k_, vT);

    attn_fwd<<<dim3(512), cb, 0, stream>>>(q_, k_, vT, attn);

    gemm_o<<<dim3(256), cb, 0, stream>>>(attn, Wob, bo, (float*)d_out);
}